// Round 6
// baseline (164.727 us; speedup 1.0000x reference)
//
#include <hip/hip_runtime.h>
#include <math.h>

#define TPB 256
#define CHP 512      // priors per match1 chunk
#define TPBS 1024    // select block size
#define RCAP 12      // select register cache (supports P <= 12*1024)
#define ROWIT 8      // m2c: iterations; block covers 16*ROWIT rows

typedef unsigned long long ull;

__device__ __forceinline__ float jac(float tx0, float ty0, float tx1, float ty1, float ta,
                                     float px0, float py0, float px1, float py1, float pa) {
    float ltx = fmaxf(tx0, px0), lty = fmaxf(ty0, py0);
    float rbx = fminf(tx1, px1), rby = fminf(ty1, py1);
    float w = fmaxf(rbx - ltx, 0.0f), h = fmaxf(rby - lty, 0.0f);
    float inter = w * h;
    return inter / (ta + pa - inter);
}

// Stage 1: per-(b,o) partial best-prior over a 512-prior chunk.
// Packed key = (ov_bits<<32) | (0xFFFFFFFF - p): ov >= 0 so float bits are
// order-monotone; ~p prefers the SMALLEST p on ties (reference first-max
// argmax). Key 0 = "no prior" and loses to any real prior. Plain stores.
template <int ON>
__global__ __launch_bounds__(TPB) void match1_kernel(
    const float* __restrict__ priors, const float* __restrict__ targets,
    int P, int O_rt, int S1, ull* __restrict__ pkeys) {
    constexpr int OMAX = (ON > 0) ? ON : 64;
    const int O = (ON > 0) ? ON : O_rt;
    const int b = blockIdx.x / S1;
    const int chunk = blockIdx.x % S1;
    const int p0 = chunk * CHP;
    const int p1 = min(p0 + CHP, P);
    const int tid = threadIdx.x;
    const int lane = tid & 63, wv = tid >> 6;

    __shared__ float s_tx0[OMAX], s_ty0[OMAX], s_tx1[OMAX], s_ty1[OMAX], s_area[OMAX];
    __shared__ ull s_wk[TPB / 64][OMAX];
    for (int o = tid; o < O; o += TPB) {
        const float* t = targets + ((size_t)b * O + o) * 5;
        float x0 = t[0], y0 = t[1], x1 = t[2], y1 = t[3];
        s_tx0[o] = x0; s_ty0[o] = y0; s_tx1[o] = x1; s_ty1[o] = y1;
        s_area[o] = (x1 - x0) * (y1 - y0);
    }
    __syncthreads();

    ull k[OMAX];
    for (int o = 0; o < O; ++o) k[o] = 0ull;
    for (int p = p0 + tid; p < p1; p += TPB) {
        float4 pr = ((const float4*)priors)[p];
        float px0 = pr.x - pr.z * 0.5f, py0 = pr.y - pr.w * 0.5f;
        float px1 = pr.x + pr.z * 0.5f, py1 = pr.y + pr.w * 0.5f;
        float pa = (px1 - px0) * (py1 - py0);
        for (int o = 0; o < O; ++o) {
            float ov = jac(s_tx0[o], s_ty0[o], s_tx1[o], s_ty1[o], s_area[o],
                           px0, py0, px1, py1, pa);
            ull kk = ((ull)__float_as_uint(ov) << 32) |
                     (ull)(0xFFFFFFFFu - (unsigned)p);
            if (kk > k[o]) k[o] = kk;
        }
    }
    for (int o = 0; o < O; ++o) {
        ull kk = k[o];
        for (int off = 32; off > 0; off >>= 1) {
            ull other = __shfl_down(kk, off, 64);
            if (other > kk) kk = other;
        }
        if (lane == 0) s_wk[wv][o] = kk;
    }
    __syncthreads();
    if (tid < O) {
        ull kk = s_wk[0][tid];
        for (int w = 1; w < TPB / 64; ++w)
            if (s_wk[w][tid] > kk) kk = s_wk[w][tid];
        pkeys[((size_t)b * O + tid) * S1 + chunk] = kk;
    }
}

// Fused match-sweep-2 + conf loss, wave-cooperative: 16 lanes per prior row.
// Lane j holds conf row elements j and j+16; lse via __shfl_xor reductions
// (2 expf/lane instead of 21/thread, no LDS round-trip, no staging barrier).
// Matching per row: lane j owns truth o=j (loop for O>16); candidate key is
//   forced (s_bp[o]==p): (bits(2.0f)<<32) | o        -> forced ties: MAX o
//   else jac:            (bits(ov)<<32) | (255 - o)  -> jac ties: MIN o
// Forced beats jac (2.0 > any IoU). Single u64 shuffle-max reduce. This
// reproduces the reference's first-max argmax + last-wins scatter exactly.
template <int ON>
__global__ __launch_bounds__(TPB) void m2c_kernel(
    const float* __restrict__ loc, const float* __restrict__ priors,
    const float* __restrict__ targets, const float* __restrict__ conf,
    const ull* __restrict__ pkeys,
    int P, int O_rt, int C, int S1, int CB2,
    float* __restrict__ mined, float* __restrict__ part_ll,
    float* __restrict__ part_pc, int* __restrict__ part_np) {
    constexpr int OMAX = (ON > 0) ? ON : 64;
    const int O = (ON > 0) ? ON : O_rt;
    const int b = blockIdx.x / CB2;
    const int chunk = blockIdx.x % CB2;
    const int r0 = chunk * (16 * ROWIT);
    const int tid = threadIdx.x;
    const int j = tid & 15;       // lane within 16-lane row group
    const int gidx = tid >> 4;    // row group within block, 0..15

    __shared__ float s_tx0[OMAX], s_ty0[OMAX], s_tx1[OMAX], s_ty1[OMAX];
    __shared__ float s_lab[OMAX], s_area[OMAX];
    __shared__ ull s_keys[OMAX];
    __shared__ int s_bp[OMAX];
    __shared__ float s_wll[TPB / 64], s_wpc[TPB / 64];
    __shared__ int s_wnp[TPB / 64];

    for (int o = tid; o < O; o += TPB) {
        const float* t = targets + ((size_t)b * O + o) * 5;
        float x0 = t[0], y0 = t[1], x1 = t[2], y1 = t[3];
        s_tx0[o] = x0; s_ty0[o] = y0; s_tx1[o] = x1; s_ty1[o] = y1;
        s_lab[o] = t[4];
        s_area[o] = (x1 - x0) * (y1 - y0);
        s_keys[o] = 0ull;
    }
    __syncthreads();
    if (tid < O * S1) {
        int o = tid / S1, s = tid % S1;
        atomicMax(&s_keys[o], pkeys[((size_t)b * O + o) * S1 + s]);
    }
    __syncthreads();
    if (tid < O)
        s_bp[tid] = (int)(0xFFFFFFFFu - (unsigned)(s_keys[tid] & 0xFFFFFFFFull));
    __syncthreads();

    float ll = 0.0f, pc = 0.0f;
    int np = 0;

    for (int it = 0; it < ROWIT; ++it) {
        const int p = r0 + it * 16 + gidx;
        const bool valid = (p < P);

        float x0 = -INFINITY, x1 = -INFINITY;
        if (valid) {
            const float* row = conf + ((size_t)b * P + p) * C;
            if (j < C) x0 = row[j];
            if (j + 16 < C) x1 = row[j + 16];
        }
        float m = fmaxf(x0, x1);
#pragma unroll
        for (int d = 1; d < 16; d <<= 1) m = fmaxf(m, __shfl_xor(m, d, 16));
        float e = expf(x0 - m) + expf(x1 - m);  // expf(-inf - m) = 0 for tail lanes
#pragma unroll
        for (int d = 1; d < 16; d <<= 1) e += __shfl_xor(e, d, 16);
        float lse = m + logf(e);

        // matching for row p
        ull key = 0ull;
        float cx = 0.f, cy = 0.f, pw = 1.f, ph = 1.f;
        if (valid) {
            float4 pr = ((const float4*)priors)[p];
            cx = pr.x; cy = pr.y; pw = pr.z; ph = pr.w;
            float px0 = cx - pw * 0.5f, py0 = cy - ph * 0.5f;
            float px1 = cx + pw * 0.5f, py1 = cy + ph * 0.5f;
            float pa = (px1 - px0) * (py1 - py0);
            for (int o = j; o < O; o += 16) {
                ull kk;
                if (s_bp[o] == p) {
                    kk = (0x40000000ull << 32) | (ull)(unsigned)o;  // 2.0f bits
                } else {
                    float ov = jac(s_tx0[o], s_ty0[o], s_tx1[o], s_ty1[o], s_area[o],
                                   px0, py0, px1, py1, pa);
                    kk = ((ull)__float_as_uint(ov) << 32) | (ull)(unsigned)(255 - o);
                }
                if (kk > key) key = kk;
            }
        }
#pragma unroll
        for (int d = 1; d < 16; d <<= 1) {
            ull kk2 = __shfl_xor(key, d, 16);
            if (kk2 > key) key = kk2;
        }
        float bto = __uint_as_float((unsigned)(key >> 32));
        int low = (int)(key & 0xFF);
        int bti = (bto == 2.0f) ? low : (255 - low);
        bti &= (OMAX > 16) ? 63 : 15;  // clamp (only hit when key==0, result unused)
        int c = (bto < 0.5f) ? 0 : ((int)s_lab[bti] + 1);

        // gathered row[c] via group shuffle
        int srcj = (c < 16) ? c : (c - 16);
        float a0 = __shfl(x0, srcj, 16);
        float a1 = __shfl(x1, srcj, 16);
        float rowc = (c < 16) ? a0 : a1;
        float lc = lse - rowc;  // >= 0 always (e >= 1 pre-log at c's scale)

        if (valid && j == 0) {
            bool pos = c > 0;
            mined[(size_t)b * P + p] = pos ? 0.0f : lc;
            if (pos) {
                pc += lc;
                ++np;
                float mx0 = s_tx0[bti], my0 = s_ty0[bti];
                float mx1 = s_tx1[bti], my1 = s_ty1[bti];
                float g0 = ((mx0 + mx1) * 0.5f - cx) / (0.1f * pw);
                float g1 = ((my0 + my1) * 0.5f - cy) / (0.1f * ph);
                float g2 = logf(fmaxf((mx1 - mx0) / pw, 1e-8f)) / 0.2f;
                float g3 = logf(fmaxf((my1 - my0) / ph, 1e-8f)) / 0.2f;
                float4 ld = ((const float4*)loc)[(size_t)b * P + p];
                float gt4[4] = {g0, g1, g2, g3};
                float lv[4] = {ld.x, ld.y, ld.z, ld.w};
#pragma unroll
                for (int q = 0; q < 4; ++q) {
                    float d = lv[q] - gt4[q];
                    float ad = fabsf(d);
                    ll += (ad < 1.0f) ? 0.5f * d * d : (ad - 0.5f);
                }
            }
        }
    }

    // reduce (ll, pc, np) across wave then block
#pragma unroll
    for (int d = 1; d < 64; d <<= 1) {
        ll += __shfl_xor(ll, d, 64);
        pc += __shfl_xor(pc, d, 64);
        np += __shfl_xor(np, d, 64);
    }
    const int wv = tid >> 6, lane = tid & 63;
    if (lane == 0) { s_wll[wv] = ll; s_wpc[wv] = pc; s_wnp[wv] = np; }
    __syncthreads();
    if (tid == 0) {
        float L = 0.f, Pc = 0.f;
        int N = 0;
        for (int w = 0; w < TPB / 64; ++w) { L += s_wll[w]; Pc += s_wpc[w]; N += s_wnp[w]; }
        part_ll[blockIdx.x] = L;
        part_pc[blockIdx.x] = Pc;
        part_np[blockIdx.x] = N;
    }
}

// One 1024-thread block per batch. mined register-cached (one global sweep).
// Radix-select k-th largest (values >= 0, bit-monotone): per-wave LDS
// histograms + log-step suffix scan. sum(top-k) = sum_{>T} + (k-cnt_gt)*T —
// exact regardless of which tied indices the reference's stable sort picks.
__global__ __launch_bounds__(TPBS) void select_kernel(
    const float* __restrict__ mined, const float* __restrict__ part_ll,
    const float* __restrict__ part_pc, const int* __restrict__ part_np,
    float* __restrict__ ll_batch, float* __restrict__ lc_batch,
    int* __restrict__ np_batch, int P, int CB, int ratio) {
    const int b = blockIdx.x, tid = threadIdx.x;
    const int wv = tid >> 6;
    constexpr int W = TPBS / 64;
    const float* v = mined + (size_t)b * P;
    const int NIT = (P + TPBS - 1) / TPBS;
    const bool cached = (NIT <= RCAP);

    __shared__ float s_rs[TPBS];
    __shared__ int s_rc[TPBS];
    __shared__ int s_hist[W * 256];
    __shared__ int s_scan[257];
    __shared__ unsigned s_bsel;
    __shared__ int s_krn;

    float rv[RCAP];
    if (cached) {
        for (int it = 0; it < NIT; ++it) {
            int p = tid + it * TPBS;
            rv[it] = (p < P) ? v[p] : 0.0f;
        }
    }

    float pll = 0.0f, ppc = 0.0f;
    int pnp = 0;
    for (int i = tid; i < CB; i += TPBS) {
        pll += part_ll[b * CB + i];
        ppc += part_pc[b * CB + i];
        pnp += part_np[b * CB + i];
    }
    s_rs[tid] = pll; s_rc[tid] = pnp;
    __syncthreads();
    for (int s = TPBS / 2; s > 0; s >>= 1) {
        if (tid < s) { s_rs[tid] += s_rs[tid + s]; s_rc[tid] += s_rc[tid + s]; }
        __syncthreads();
    }
    const float ll_sum = s_rs[0];
    const int npos = s_rc[0];
    __syncthreads();
    s_rs[tid] = ppc;
    __syncthreads();
    for (int s = TPBS / 2; s > 0; s >>= 1) {
        if (tid < s) s_rs[tid] += s_rs[tid + s];
        __syncthreads();
    }
    const float sum_pos = s_rs[0];
    __syncthreads();

    const int k = min(ratio * npos, P - npos);
    if (tid == 0) {
        ll_batch[b] = ll_sum;
        np_batch[b] = npos;
    }
    if (k <= 0) {
        if (tid == 0) lc_batch[b] = sum_pos;
        return;
    }

    unsigned prefix = 0u;
    int kr = k;
    for (int pass = 0; pass < 4; ++pass) {
        const int shift = 24 - 8 * pass;
        const unsigned mask = (pass == 0) ? 0u : (0xFFFFFFFFu << (32 - 8 * pass));
        for (int i = tid; i < W * 256; i += TPBS) s_hist[i] = 0;
        __syncthreads();
        for (int it = 0; it < NIT; ++it) {
            int p = tid + it * TPBS;
            if (p < P) {
                unsigned u = __float_as_uint(cached ? rv[it] : v[p]);
                if ((u & mask) == prefix)
                    atomicAdd(&s_hist[wv * 256 + ((u >> shift) & 0xFF)], 1);
            }
        }
        __syncthreads();
        if (tid < 256) {
            int h = 0;
            for (int w = 0; w < W; ++w) h += s_hist[w * 256 + tid];
            s_scan[tid] = h;
        }
        if (tid == 0) s_scan[256] = 0;
        __syncthreads();
        for (int d = 1; d < 256; d <<= 1) {
            int val = 0;
            if (tid < 256) val = s_scan[tid] + ((tid + d < 256) ? s_scan[tid + d] : 0);
            __syncthreads();
            if (tid < 256) s_scan[tid] = val;
            __syncthreads();
        }
        if (tid < 256) {
            int sge = s_scan[tid];
            int sgt = s_scan[tid + 1];
            if (sge >= kr && sgt < kr) {  // exactly one tid satisfies
                s_bsel = (unsigned)tid;
                s_krn = kr - sgt;
            }
        }
        __syncthreads();
        prefix |= s_bsel << shift;
        kr = s_krn;
        __syncthreads();
    }
    const float T = __uint_as_float(prefix);  // exact k-th largest value
    float lsum = 0.0f;
    int lcnt = 0;
    for (int it = 0; it < NIT; ++it) {
        int p = tid + it * TPBS;
        if (p < P) {
            float x = cached ? rv[it] : v[p];
            if (x > T) { lsum += x; ++lcnt; }
        }
    }
    s_rs[tid] = lsum; s_rc[tid] = lcnt;
    __syncthreads();
    for (int s = TPBS / 2; s > 0; s >>= 1) {
        if (tid < s) { s_rs[tid] += s_rs[tid + s]; s_rc[tid] += s_rc[tid + s]; }
        __syncthreads();
    }
    if (tid == 0) lc_batch[b] = sum_pos + s_rs[0] + (float)(k - s_rc[0]) * T;
}

__global__ __launch_bounds__(TPB) void finalize_kernel(
    const float* __restrict__ ll_batch, const int* __restrict__ np_batch,
    const float* __restrict__ lc_batch, int B, float* __restrict__ out) {
    const int tid = threadIdx.x;
    __shared__ float s_l[TPB], s_c[TPB];
    __shared__ int s_n[TPB];
    float l = 0.0f, c = 0.0f;
    int n = 0;
    for (int i = tid; i < B; i += TPB) {
        l += ll_batch[i];
        c += lc_batch[i];
        n += np_batch[i];
    }
    s_l[tid] = l; s_c[tid] = c; s_n[tid] = n;
    __syncthreads();
    for (int s = TPB / 2; s > 0; s >>= 1) {
        if (tid < s) {
            s_l[tid] += s_l[tid + s];
            s_c[tid] += s_c[tid + s];
            s_n[tid] += s_n[tid + s];
        }
        __syncthreads();
    }
    if (tid == 0) {
        float N = (float)s_n[0];
        out[0] = s_l[0] / N;
        out[1] = s_c[0] / N;
    }
}

extern "C" void kernel_launch(void* const* d_in, const int* in_sizes, int n_in,
                              void* d_out, int out_size, void* d_ws, size_t ws_size,
                              hipStream_t stream) {
    const float* loc = (const float*)d_in[0];
    const float* conf = (const float*)d_in[1];
    const float* priors = (const float*)d_in[2];
    const float* targets = (const float*)d_in[3];

    const int P = in_sizes[2] / 4;
    const int B = in_sizes[0] / (P * 4);
    const int C = in_sizes[1] / (in_sizes[0] / 4);  // conf / (B*P)
    const int O = in_sizes[3] / (B * 5);
    const size_t BP = (size_t)B * P;
    const int S1 = (P + CHP - 1) / CHP;                  // match1 chunks per batch
    const int CB2 = (P + 16 * ROWIT - 1) / (16 * ROWIT); // m2c chunks per batch

    // ws layout (8B-aligned first; everything fully written before read):
    ull* pkeys = (ull*)d_ws;                                // B*O*S1 u64
    float* mined = (float*)(pkeys + (size_t)B * O * S1);    // BP f32
    float* part_ll = mined + BP;                            // B*CB2 f32
    float* part_pc = part_ll + (size_t)B * CB2;             // B*CB2 f32
    int* part_np = (int*)(part_pc + (size_t)B * CB2);       // B*CB2 i32
    float* ll_batch = (float*)(part_np + (size_t)B * CB2);  // B f32
    float* lc_batch = ll_batch + B;                         // B f32
    int* np_batch = (int*)(lc_batch + B);                   // B i32

    if (O == 8) {
        match1_kernel<8><<<B * S1, TPB, 0, stream>>>(priors, targets, P, O, S1, pkeys);
        m2c_kernel<8><<<B * CB2, TPB, 0, stream>>>(
            loc, priors, targets, conf, pkeys, P, O, C, S1, CB2,
            mined, part_ll, part_pc, part_np);
    } else {
        match1_kernel<0><<<B * S1, TPB, 0, stream>>>(priors, targets, P, O, S1, pkeys);
        m2c_kernel<0><<<B * CB2, TPB, 0, stream>>>(
            loc, priors, targets, conf, pkeys, P, O, C, S1, CB2,
            mined, part_ll, part_pc, part_np);
    }

    select_kernel<<<B, TPBS, 0, stream>>>(mined, part_ll, part_pc, part_np,
                                          ll_batch, lc_batch, np_batch, P, CB2, 3);

    finalize_kernel<<<1, TPB, 0, stream>>>(ll_batch, np_batch, lc_batch, B,
                                           (float*)d_out);
}

// Round 7
// 133.318 us; speedup vs baseline: 1.2356x; 1.2356x over previous
//
#include <hip/hip_runtime.h>
#include <math.h>

#define TPB 256
#define CHP 512      // priors per match1 chunk
#define TPBS 1024    // select block size
#define RCAP 12      // select register cache (supports P <= 12*1024)

typedef unsigned long long ull;
typedef float pf4 __attribute__((ext_vector_type(4), aligned(4)));  // 4B-aligned float4

__device__ __forceinline__ float jac(float tx0, float ty0, float tx1, float ty1, float ta,
                                     float px0, float py0, float px1, float py1, float pa) {
    float ltx = fmaxf(tx0, px0), lty = fmaxf(ty0, py0);
    float rbx = fminf(tx1, px1), rby = fminf(ty1, py1);
    float w = fmaxf(rbx - ltx, 0.0f), h = fmaxf(rby - lty, 0.0f);
    float inter = w * h;
    return inter / (ta + pa - inter);
}

// Stage 1: per-(b,o) partial best-prior over a 512-prior chunk.
// Packed key = (ov_bits<<32) | (0xFFFFFFFF - p): ov >= 0 so float bits are
// order-monotone; ~p prefers the SMALLEST p on ties (reference first-max
// argmax). Key 0 = "no prior" and loses to any real prior. Plain stores.
template <int ON>
__global__ __launch_bounds__(TPB) void match1_kernel(
    const float* __restrict__ priors, const float* __restrict__ targets,
    int P, int O_rt, int S1, ull* __restrict__ pkeys) {
    constexpr int OMAX = (ON > 0) ? ON : 64;
    const int O = (ON > 0) ? ON : O_rt;
    const int b = blockIdx.x / S1;
    const int chunk = blockIdx.x % S1;
    const int p0 = chunk * CHP;
    const int p1 = min(p0 + CHP, P);
    const int tid = threadIdx.x;
    const int lane = tid & 63, wv = tid >> 6;

    __shared__ float s_tx0[OMAX], s_ty0[OMAX], s_tx1[OMAX], s_ty1[OMAX], s_area[OMAX];
    __shared__ ull s_wk[TPB / 64][OMAX];
    for (int o = tid; o < O; o += TPB) {
        const float* t = targets + ((size_t)b * O + o) * 5;
        float x0 = t[0], y0 = t[1], x1 = t[2], y1 = t[3];
        s_tx0[o] = x0; s_ty0[o] = y0; s_tx1[o] = x1; s_ty1[o] = y1;
        s_area[o] = (x1 - x0) * (y1 - y0);
    }
    __syncthreads();

    ull k[OMAX];
    for (int o = 0; o < O; ++o) k[o] = 0ull;
    for (int p = p0 + tid; p < p1; p += TPB) {
        float4 pr = ((const float4*)priors)[p];
        float px0 = pr.x - pr.z * 0.5f, py0 = pr.y - pr.w * 0.5f;
        float px1 = pr.x + pr.z * 0.5f, py1 = pr.y + pr.w * 0.5f;
        float pa = (px1 - px0) * (py1 - py0);
        for (int o = 0; o < O; ++o) {
            float ov = jac(s_tx0[o], s_ty0[o], s_tx1[o], s_ty1[o], s_area[o],
                           px0, py0, px1, py1, pa);
            ull kk = ((ull)__float_as_uint(ov) << 32) |
                     (ull)(0xFFFFFFFFu - (unsigned)p);
            if (kk > k[o]) k[o] = kk;
        }
    }
    for (int o = 0; o < O; ++o) {
        ull kk = k[o];
        for (int off = 32; off > 0; off >>= 1) {
            ull other = __shfl_down(kk, off, 64);
            if (other > kk) kk = other;
        }
        if (lane == 0) s_wk[wv][o] = kk;
    }
    __syncthreads();
    if (tid < O) {
        ull kk = s_wk[0][tid];
        for (int w = 1; w < TPB / 64; ++w)
            if (s_wk[w][tid] > kk) kk = s_wk[w][tid];
        pkeys[((size_t)b * O + tid) * S1 + chunk] = kk;
    }
}

// Fused match-sweep-2 + conf loss. Thread-per-row, register-resident:
// the 21-float conf row is loaded directly from global as 5 packed
// (4B-aligned) dwordx4 + 1 dword — no LDS staging, no per-tile barrier,
// no cross-lane shuffles (the R6 regression: 454k ds_bpermute bank
// conflicts + 65% VALUBusy). Setup barriers only. Plain partial stores.
template <int ON, int CN>
__global__ __launch_bounds__(TPB) void m2c_kernel(
    const float* __restrict__ loc, const float* __restrict__ priors,
    const float* __restrict__ targets, const float* __restrict__ conf,
    const ull* __restrict__ pkeys,
    int P, int O_rt, int C_rt, int S1, int CB2,
    float* __restrict__ mined, float* __restrict__ part_ll,
    float* __restrict__ part_pc, int* __restrict__ part_np) {
    constexpr int OMAX = (ON > 0) ? ON : 64;
    constexpr int CC = (CN > 0) ? CN : 32;
    const int O = (ON > 0) ? ON : O_rt;
    const int C = (CN > 0) ? CN : C_rt;
    const int b = blockIdx.x / CB2;
    const int chunk = blockIdx.x % CB2;
    const int p = chunk * TPB + threadIdx.x;
    const int tid = threadIdx.x;

    __shared__ float s_tx0[OMAX], s_ty0[OMAX], s_tx1[OMAX], s_ty1[OMAX];
    __shared__ float s_lab[OMAX], s_area[OMAX];
    __shared__ ull s_keys[OMAX];
    __shared__ int s_bp[OMAX];
    __shared__ float s_wll[TPB / 64], s_wpc[TPB / 64];
    __shared__ int s_wnp[TPB / 64];

    for (int o = tid; o < O; o += TPB) {
        const float* t = targets + ((size_t)b * O + o) * 5;
        float x0 = t[0], y0 = t[1], x1 = t[2], y1 = t[3];
        s_tx0[o] = x0; s_ty0[o] = y0; s_tx1[o] = x1; s_ty1[o] = y1;
        s_lab[o] = t[4];
        s_area[o] = (x1 - x0) * (y1 - y0);
        s_keys[o] = 0ull;
    }
    __syncthreads();
    if (tid < O * S1) {
        int o = tid / S1, s = tid % S1;
        atomicMax(&s_keys[o], pkeys[((size_t)b * O + o) * S1 + s]);
    }
    __syncthreads();
    if (tid < O)
        s_bp[tid] = (int)(0xFFFFFFFFu - (unsigned)(s_keys[tid] & 0xFFFFFFFFull));
    __syncthreads();

    float ll = 0.0f, pc = 0.0f;
    int np = 0;

    if (p < P) {
        // ---- load conf row into registers (5 x dwordx4 + 1 x dword) ----
        float rv[CC];
        const float* row = conf + ((size_t)b * P + p) * C;
        if (CN > 0) {
#pragma unroll
            for (int q = 0; q < CN / 4; ++q) {
                pf4 v = *(const pf4*)(row + 4 * q);
#pragma unroll
                for (int e = 0; e < 4; ++e) rv[4 * q + e] = v[e];
            }
#pragma unroll
            for (int j = (CN / 4) * 4; j < CN; ++j) rv[j] = row[j];
        } else {
            for (int j = 0; j < C; ++j) rv[j] = row[j];
        }

        // lse (same accumulation order as the verified R4 kernel)
        float m = rv[0];
#pragma unroll
        for (int j = 1; j < CC; ++j) { if (CN > 0 || j < C) m = fmaxf(m, rv[j]); }
        float s = 0.0f;
#pragma unroll
        for (int j = 0; j < CC; ++j) { if (CN > 0 || j < C) s += expf(rv[j] - m); }
        float lse = m + logf(s);

        // ---- matching sweep ----
        float4 pr = ((const float4*)priors)[p];
        float cx = pr.x, cy = pr.y, pw = pr.z, ph = pr.w;
        float px0 = cx - pw * 0.5f, py0 = cy - ph * 0.5f;
        float px1 = cx + pw * 0.5f, py1 = cy + ph * 0.5f;
        float pa = (px1 - px0) * (py1 - py0);
        float bto = -1.0f;
        int bti = 0;
        for (int o = 0; o < O; ++o) {
            float ov = jac(s_tx0[o], s_ty0[o], s_tx1[o], s_ty1[o], s_area[o],
                           px0, py0, px1, py1, pa);
            if (ov > bto) { bto = ov; bti = o; }  // first-max over o
        }
        for (int o = 0; o < O; ++o) {
            if (s_bp[o] == p) { bto = 2.0f; bti = o; }  // last o wins (ref scatter)
        }
        int c = (bto < 0.5f) ? 0 : ((int)s_lab[bti] + 1);

        // gathered rv[c] via unrolled select chain (no LDS, no shuffle)
        float rowc = rv[0];
#pragma unroll
        for (int j = 1; j < CC; ++j) { if (CN > 0 || j < C) { if (c == j) rowc = rv[j]; } }
        float lc = lse - rowc;  // >= 0 always (s >= 1)

        bool pos = c > 0;
        mined[(size_t)b * P + p] = pos ? 0.0f : lc;
        if (pos) {
            pc = lc;
            np = 1;
            float mx0 = s_tx0[bti], my0 = s_ty0[bti];
            float mx1 = s_tx1[bti], my1 = s_ty1[bti];
            float g0 = ((mx0 + mx1) * 0.5f - cx) / (0.1f * pw);
            float g1 = ((my0 + my1) * 0.5f - cy) / (0.1f * ph);
            float g2 = logf(fmaxf((mx1 - mx0) / pw, 1e-8f)) / 0.2f;
            float g3 = logf(fmaxf((my1 - my0) / ph, 1e-8f)) / 0.2f;
            float4 ld = ((const float4*)loc)[(size_t)b * P + p];
            float gt4[4] = {g0, g1, g2, g3};
            float lv[4] = {ld.x, ld.y, ld.z, ld.w};
#pragma unroll
            for (int q = 0; q < 4; ++q) {
                float d = lv[q] - gt4[q];
                float ad = fabsf(d);
                ll += (ad < 1.0f) ? 0.5f * d * d : (ad - 0.5f);
            }
        }
    }

    // reduce (ll, pc, np): wave shuffle then tiny LDS combine
#pragma unroll
    for (int d = 1; d < 64; d <<= 1) {
        ll += __shfl_xor(ll, d, 64);
        pc += __shfl_xor(pc, d, 64);
        np += __shfl_xor(np, d, 64);
    }
    const int wv = tid >> 6, lane = tid & 63;
    if (lane == 0) { s_wll[wv] = ll; s_wpc[wv] = pc; s_wnp[wv] = np; }
    __syncthreads();
    if (tid == 0) {
        float L = 0.f, Pc = 0.f;
        int N = 0;
        for (int w = 0; w < TPB / 64; ++w) { L += s_wll[w]; Pc += s_wpc[w]; N += s_wnp[w]; }
        part_ll[blockIdx.x] = L;
        part_pc[blockIdx.x] = Pc;
        part_np[blockIdx.x] = N;
    }
}

// One 1024-thread block per batch. mined register-cached (one global sweep).
// Radix-select k-th largest (values >= 0, bit-monotone): per-wave LDS
// histograms + log-step suffix scan. sum(top-k) = sum_{>T} + (k-cnt_gt)*T —
// exact regardless of which tied indices the reference's stable sort picks.
__global__ __launch_bounds__(TPBS) void select_kernel(
    const float* __restrict__ mined, const float* __restrict__ part_ll,
    const float* __restrict__ part_pc, const int* __restrict__ part_np,
    float* __restrict__ ll_batch, float* __restrict__ lc_batch,
    int* __restrict__ np_batch, int P, int CB, int ratio) {
    const int b = blockIdx.x, tid = threadIdx.x;
    const int wv = tid >> 6;
    constexpr int W = TPBS / 64;
    const float* v = mined + (size_t)b * P;
    const int NIT = (P + TPBS - 1) / TPBS;
    const bool cached = (NIT <= RCAP);

    __shared__ float s_rs[TPBS];
    __shared__ int s_rc[TPBS];
    __shared__ int s_hist[W * 256];
    __shared__ int s_scan[257];
    __shared__ unsigned s_bsel;
    __shared__ int s_krn;

    float rv[RCAP];
    if (cached) {
        for (int it = 0; it < NIT; ++it) {
            int p = tid + it * TPBS;
            rv[it] = (p < P) ? v[p] : 0.0f;
        }
    }

    float pll = 0.0f, ppc = 0.0f;
    int pnp = 0;
    for (int i = tid; i < CB; i += TPBS) {
        pll += part_ll[b * CB + i];
        ppc += part_pc[b * CB + i];
        pnp += part_np[b * CB + i];
    }
    s_rs[tid] = pll; s_rc[tid] = pnp;
    __syncthreads();
    for (int s = TPBS / 2; s > 0; s >>= 1) {
        if (tid < s) { s_rs[tid] += s_rs[tid + s]; s_rc[tid] += s_rc[tid + s]; }
        __syncthreads();
    }
    const float ll_sum = s_rs[0];
    const int npos = s_rc[0];
    __syncthreads();
    s_rs[tid] = ppc;
    __syncthreads();
    for (int s = TPBS / 2; s > 0; s >>= 1) {
        if (tid < s) s_rs[tid] += s_rs[tid + s];
        __syncthreads();
    }
    const float sum_pos = s_rs[0];
    __syncthreads();

    const int k = min(ratio * npos, P - npos);
    if (tid == 0) {
        ll_batch[b] = ll_sum;
        np_batch[b] = npos;
    }
    if (k <= 0) {
        if (tid == 0) lc_batch[b] = sum_pos;
        return;
    }

    unsigned prefix = 0u;
    int kr = k;
    for (int pass = 0; pass < 4; ++pass) {
        const int shift = 24 - 8 * pass;
        const unsigned mask = (pass == 0) ? 0u : (0xFFFFFFFFu << (32 - 8 * pass));
        for (int i = tid; i < W * 256; i += TPBS) s_hist[i] = 0;
        __syncthreads();
        for (int it = 0; it < NIT; ++it) {
            int p = tid + it * TPBS;
            if (p < P) {
                unsigned u = __float_as_uint(cached ? rv[it] : v[p]);
                if ((u & mask) == prefix)
                    atomicAdd(&s_hist[wv * 256 + ((u >> shift) & 0xFF)], 1);
            }
        }
        __syncthreads();
        if (tid < 256) {
            int h = 0;
            for (int w = 0; w < W; ++w) h += s_hist[w * 256 + tid];
            s_scan[tid] = h;
        }
        if (tid == 0) s_scan[256] = 0;
        __syncthreads();
        for (int d = 1; d < 256; d <<= 1) {
            int val = 0;
            if (tid < 256) val = s_scan[tid] + ((tid + d < 256) ? s_scan[tid + d] : 0);
            __syncthreads();
            if (tid < 256) s_scan[tid] = val;
            __syncthreads();
        }
        if (tid < 256) {
            int sge = s_scan[tid];
            int sgt = s_scan[tid + 1];
            if (sge >= kr && sgt < kr) {  // exactly one tid satisfies
                s_bsel = (unsigned)tid;
                s_krn = kr - sgt;
            }
        }
        __syncthreads();
        prefix |= s_bsel << shift;
        kr = s_krn;
        __syncthreads();
    }
    const float T = __uint_as_float(prefix);  // exact k-th largest value
    float lsum = 0.0f;
    int lcnt = 0;
    for (int it = 0; it < NIT; ++it) {
        int p = tid + it * TPBS;
        if (p < P) {
            float x = cached ? rv[it] : v[p];
            if (x > T) { lsum += x; ++lcnt; }
        }
    }
    s_rs[tid] = lsum; s_rc[tid] = lcnt;
    __syncthreads();
    for (int s = TPBS / 2; s > 0; s >>= 1) {
        if (tid < s) { s_rs[tid] += s_rs[tid + s]; s_rc[tid] += s_rc[tid + s]; }
        __syncthreads();
    }
    if (tid == 0) lc_batch[b] = sum_pos + s_rs[0] + (float)(k - s_rc[0]) * T;
}

__global__ __launch_bounds__(TPB) void finalize_kernel(
    const float* __restrict__ ll_batch, const int* __restrict__ np_batch,
    const float* __restrict__ lc_batch, int B, float* __restrict__ out) {
    const int tid = threadIdx.x;
    __shared__ float s_l[TPB], s_c[TPB];
    __shared__ int s_n[TPB];
    float l = 0.0f, c = 0.0f;
    int n = 0;
    for (int i = tid; i < B; i += TPB) {
        l += ll_batch[i];
        c += lc_batch[i];
        n += np_batch[i];
    }
    s_l[tid] = l; s_c[tid] = c; s_n[tid] = n;
    __syncthreads();
    for (int s = TPB / 2; s > 0; s >>= 1) {
        if (tid < s) {
            s_l[tid] += s_l[tid + s];
            s_c[tid] += s_c[tid + s];
            s_n[tid] += s_n[tid + s];
        }
        __syncthreads();
    }
    if (tid == 0) {
        float N = (float)s_n[0];
        out[0] = s_l[0] / N;
        out[1] = s_c[0] / N;
    }
}

extern "C" void kernel_launch(void* const* d_in, const int* in_sizes, int n_in,
                              void* d_out, int out_size, void* d_ws, size_t ws_size,
                              hipStream_t stream) {
    const float* loc = (const float*)d_in[0];
    const float* conf = (const float*)d_in[1];
    const float* priors = (const float*)d_in[2];
    const float* targets = (const float*)d_in[3];

    const int P = in_sizes[2] / 4;
    const int B = in_sizes[0] / (P * 4);
    const int C = in_sizes[1] / (in_sizes[0] / 4);  // conf / (B*P)
    const int O = in_sizes[3] / (B * 5);
    const size_t BP = (size_t)B * P;
    const int S1 = (P + CHP - 1) / CHP;    // match1 chunks per batch
    const int CB2 = (P + TPB - 1) / TPB;   // m2c chunks per batch

    // ws layout (8B-aligned first; everything fully written before read):
    ull* pkeys = (ull*)d_ws;                                // B*O*S1 u64
    float* mined = (float*)(pkeys + (size_t)B * O * S1);    // BP f32
    float* part_ll = mined + BP;                            // B*CB2 f32
    float* part_pc = part_ll + (size_t)B * CB2;             // B*CB2 f32
    int* part_np = (int*)(part_pc + (size_t)B * CB2);       // B*CB2 i32
    float* ll_batch = (float*)(part_np + (size_t)B * CB2);  // B f32
    float* lc_batch = ll_batch + B;                         // B f32
    int* np_batch = (int*)(lc_batch + B);                   // B i32

    if (O == 8) {
        match1_kernel<8><<<B * S1, TPB, 0, stream>>>(priors, targets, P, O, S1, pkeys);
        if (C == 21) {
            m2c_kernel<8, 21><<<B * CB2, TPB, 0, stream>>>(
                loc, priors, targets, conf, pkeys, P, O, C, S1, CB2,
                mined, part_ll, part_pc, part_np);
        } else {
            m2c_kernel<8, 0><<<B * CB2, TPB, 0, stream>>>(
                loc, priors, targets, conf, pkeys, P, O, C, S1, CB2,
                mined, part_ll, part_pc, part_np);
        }
    } else {
        match1_kernel<0><<<B * S1, TPB, 0, stream>>>(priors, targets, P, O, S1, pkeys);
        m2c_kernel<0, 0><<<B * CB2, TPB, 0, stream>>>(
            loc, priors, targets, conf, pkeys, P, O, C, S1, CB2,
            mined, part_ll, part_pc, part_np);
    }

    select_kernel<<<B, TPBS, 0, stream>>>(mined, part_ll, part_pc, part_np,
                                          ll_batch, lc_batch, np_batch, P, CB2, 3);

    finalize_kernel<<<1, TPB, 0, stream>>>(ll_batch, np_batch, lc_batch, B,
                                           (float*)d_out);
}

// Round 8
// 133.062 us; speedup vs baseline: 1.2380x; 1.0019x over previous
//
#include <hip/hip_runtime.h>
#include <math.h>

#define TPB 256
#define CHP 512      // priors per match1 chunk
#define TPBS 1024    // select block size
#define RCAP 12      // select register cache (supports P <= 12*1024)

typedef unsigned long long ull;
typedef float pf4 __attribute__((ext_vector_type(4), aligned(4)));  // 4B-aligned float4

__device__ __forceinline__ float jac(float tx0, float ty0, float tx1, float ty1, float ta,
                                     float px0, float py0, float px1, float py1, float pa) {
    float ltx = fmaxf(tx0, px0), lty = fmaxf(ty0, py0);
    float rbx = fminf(tx1, px1), rby = fminf(ty1, py1);
    float w = fmaxf(rbx - ltx, 0.0f), h = fmaxf(rby - lty, 0.0f);
    float inter = w * h;
    return inter / (ta + pa - inter);
}

// Stage 1: per-(b,o) partial best-prior over a 512-prior chunk.
// Packed key = (ov_bits<<32) | (0xFFFFFFFF - p): ov >= 0 so float bits are
// order-monotone; ~p prefers the SMALLEST p on ties (reference first-max
// argmax). Key 0 = "no prior" and loses to any real prior. Plain stores.
template <int ON>
__global__ __launch_bounds__(TPB) void match1_kernel(
    const float* __restrict__ priors, const float* __restrict__ targets,
    int P, int O_rt, int S1, ull* __restrict__ pkeys) {
    constexpr int OMAX = (ON > 0) ? ON : 64;
    const int O = (ON > 0) ? ON : O_rt;
    const int b = blockIdx.x / S1;
    const int chunk = blockIdx.x % S1;
    const int p0 = chunk * CHP;
    const int p1 = min(p0 + CHP, P);
    const int tid = threadIdx.x;
    const int lane = tid & 63, wv = tid >> 6;

    __shared__ float s_tx0[OMAX], s_ty0[OMAX], s_tx1[OMAX], s_ty1[OMAX], s_area[OMAX];
    __shared__ ull s_wk[TPB / 64][OMAX];
    for (int o = tid; o < O; o += TPB) {
        const float* t = targets + ((size_t)b * O + o) * 5;
        float x0 = t[0], y0 = t[1], x1 = t[2], y1 = t[3];
        s_tx0[o] = x0; s_ty0[o] = y0; s_tx1[o] = x1; s_ty1[o] = y1;
        s_area[o] = (x1 - x0) * (y1 - y0);
    }
    __syncthreads();

    ull k[OMAX];
    for (int o = 0; o < O; ++o) k[o] = 0ull;
    for (int p = p0 + tid; p < p1; p += TPB) {
        float4 pr = ((const float4*)priors)[p];
        float px0 = pr.x - pr.z * 0.5f, py0 = pr.y - pr.w * 0.5f;
        float px1 = pr.x + pr.z * 0.5f, py1 = pr.y + pr.w * 0.5f;
        float pa = (px1 - px0) * (py1 - py0);
        for (int o = 0; o < O; ++o) {
            float ov = jac(s_tx0[o], s_ty0[o], s_tx1[o], s_ty1[o], s_area[o],
                           px0, py0, px1, py1, pa);
            ull kk = ((ull)__float_as_uint(ov) << 32) |
                     (ull)(0xFFFFFFFFu - (unsigned)p);
            if (kk > k[o]) k[o] = kk;
        }
    }
    for (int o = 0; o < O; ++o) {
        ull kk = k[o];
        for (int off = 32; off > 0; off >>= 1) {
            ull other = __shfl_down(kk, off, 64);
            if (other > kk) kk = other;
        }
        if (lane == 0) s_wk[wv][o] = kk;
    }
    __syncthreads();
    if (tid < O) {
        ull kk = s_wk[0][tid];
        for (int w = 1; w < TPB / 64; ++w)
            if (s_wk[w][tid] > kk) kk = s_wk[w][tid];
        pkeys[((size_t)b * O + tid) * S1 + chunk] = kk;
    }
}

// Fused match-sweep-2 + conf loss. Thread-per-row, register-resident.
// The 21-float conf row is loaded FIRST (5 packed 4B-aligned dwordx4 + 1
// dword) so global latency overlaps the LDS setup + its 3 barriers.
// No per-tile barriers, no cross-lane shuffles in the hot path.
template <int ON, int CN>
__global__ __launch_bounds__(TPB) void m2c_kernel(
    const float* __restrict__ loc, const float* __restrict__ priors,
    const float* __restrict__ targets, const float* __restrict__ conf,
    const ull* __restrict__ pkeys,
    int P, int O_rt, int C_rt, int S1, int CB2,
    float* __restrict__ mined, float* __restrict__ part_ll,
    float* __restrict__ part_pc, int* __restrict__ part_np) {
    constexpr int OMAX = (ON > 0) ? ON : 64;
    constexpr int CC = (CN > 0) ? CN : 32;
    const int O = (ON > 0) ? ON : O_rt;
    const int C = (CN > 0) ? CN : C_rt;
    const int b = blockIdx.x / CB2;
    const int chunk = blockIdx.x % CB2;
    const int tid = threadIdx.x;
    const int p = chunk * TPB + tid;
    const bool pv = (p < P);

    __shared__ float s_tx0[OMAX], s_ty0[OMAX], s_tx1[OMAX], s_ty1[OMAX];
    __shared__ float s_lab[OMAX], s_area[OMAX];
    __shared__ ull s_keys[OMAX];
    __shared__ int s_bp[OMAX];
    __shared__ float s_wll[TPB / 64], s_wpc[TPB / 64];
    __shared__ int s_wnp[TPB / 64];

    // ---- issue conf-row + prior loads FIRST (latency overlaps setup) ----
    float rv[CC];
    float4 pr4 = make_float4(0.f, 0.f, 1.f, 1.f);
    if (pv) {
        const float* row = conf + ((size_t)b * P + p) * C;
        if (CN > 0) {
#pragma unroll
            for (int q = 0; q < CN / 4; ++q) {
                pf4 v = *(const pf4*)(row + 4 * q);
#pragma unroll
                for (int e = 0; e < 4; ++e) rv[4 * q + e] = v[e];
            }
#pragma unroll
            for (int j = (CN / 4) * 4; j < CN; ++j) rv[j] = row[j];
        } else {
            for (int j = 0; j < C; ++j) rv[j] = row[j];
        }
        pr4 = ((const float4*)priors)[p];
    }

    // ---- LDS setup ----
    for (int o = tid; o < O; o += TPB) {
        const float* t = targets + ((size_t)b * O + o) * 5;
        float x0 = t[0], y0 = t[1], x1 = t[2], y1 = t[3];
        s_tx0[o] = x0; s_ty0[o] = y0; s_tx1[o] = x1; s_ty1[o] = y1;
        s_lab[o] = t[4];
        s_area[o] = (x1 - x0) * (y1 - y0);
        s_keys[o] = 0ull;
    }
    __syncthreads();
    if (tid < O * S1) {
        int o = tid / S1, s = tid % S1;
        atomicMax(&s_keys[o], pkeys[((size_t)b * O + o) * S1 + s]);
    }
    __syncthreads();
    if (tid < O)
        s_bp[tid] = (int)(0xFFFFFFFFu - (unsigned)(s_keys[tid] & 0xFFFFFFFFull));
    __syncthreads();

    float ll = 0.0f, pc = 0.0f;
    int np = 0;

    if (pv) {
        // lse (same accumulation order as the verified R4 kernel)
        float m = rv[0];
#pragma unroll
        for (int j = 1; j < CC; ++j) { if (CN > 0 || j < C) m = fmaxf(m, rv[j]); }
        float s = 0.0f;
#pragma unroll
        for (int j = 0; j < CC; ++j) { if (CN > 0 || j < C) s += expf(rv[j] - m); }
        float lse = m + logf(s);

        // ---- matching sweep ----
        float cx = pr4.x, cy = pr4.y, pw = pr4.z, ph = pr4.w;
        float px0 = cx - pw * 0.5f, py0 = cy - ph * 0.5f;
        float px1 = cx + pw * 0.5f, py1 = cy + ph * 0.5f;
        float pa = (px1 - px0) * (py1 - py0);
        float bto = -1.0f;
        int bti = 0;
        for (int o = 0; o < O; ++o) {
            float ov = jac(s_tx0[o], s_ty0[o], s_tx1[o], s_ty1[o], s_area[o],
                           px0, py0, px1, py1, pa);
            if (ov > bto) { bto = ov; bti = o; }  // first-max over o
        }
        for (int o = 0; o < O; ++o) {
            if (s_bp[o] == p) { bto = 2.0f; bti = o; }  // last o wins (ref scatter)
        }
        int c = (bto < 0.5f) ? 0 : ((int)s_lab[bti] + 1);

        // gathered rv[c] via unrolled select chain (no LDS, no shuffle)
        float rowc = rv[0];
#pragma unroll
        for (int j = 1; j < CC; ++j) { if (CN > 0 || j < C) { if (c == j) rowc = rv[j]; } }
        float lc = lse - rowc;  // >= 0 always (s >= 1)

        bool pos = c > 0;
        mined[(size_t)b * P + p] = pos ? 0.0f : lc;
        if (pos) {
            pc = lc;
            np = 1;
            float mx0 = s_tx0[bti], my0 = s_ty0[bti];
            float mx1 = s_tx1[bti], my1 = s_ty1[bti];
            float g0 = ((mx0 + mx1) * 0.5f - cx) / (0.1f * pw);
            float g1 = ((my0 + my1) * 0.5f - cy) / (0.1f * ph);
            float g2 = logf(fmaxf((mx1 - mx0) / pw, 1e-8f)) / 0.2f;
            float g3 = logf(fmaxf((my1 - my0) / ph, 1e-8f)) / 0.2f;
            float4 ld = ((const float4*)loc)[(size_t)b * P + p];
            float gt4[4] = {g0, g1, g2, g3};
            float lv[4] = {ld.x, ld.y, ld.z, ld.w};
#pragma unroll
            for (int q = 0; q < 4; ++q) {
                float d = lv[q] - gt4[q];
                float ad = fabsf(d);
                ll += (ad < 1.0f) ? 0.5f * d * d : (ad - 0.5f);
            }
        }
    }

    // reduce (ll, pc, np): wave shuffle then tiny LDS combine
#pragma unroll
    for (int d = 1; d < 64; d <<= 1) {
        ll += __shfl_xor(ll, d, 64);
        pc += __shfl_xor(pc, d, 64);
        np += __shfl_xor(np, d, 64);
    }
    const int wv = tid >> 6, lane = tid & 63;
    if (lane == 0) { s_wll[wv] = ll; s_wpc[wv] = pc; s_wnp[wv] = np; }
    __syncthreads();
    if (tid == 0) {
        float L = 0.f, Pc = 0.f;
        int N = 0;
        for (int w = 0; w < TPB / 64; ++w) { L += s_wll[w]; Pc += s_wpc[w]; N += s_wnp[w]; }
        part_ll[blockIdx.x] = L;
        part_pc[blockIdx.x] = Pc;
        part_np[blockIdx.x] = N;
    }
}

// One 1024-thread block per batch, BARRIER-DIET version (~20 barriers vs
// ~130): all reductions are wave __shfl_xor + one 16-slot LDS combine; the
// radix bin-pick uses an intra-wave shuffle suffix-scan + 4-wave LDS fixup.
// mined register-cached (one global sweep). Radix-select k-th largest
// (values >= 0, bit-monotone); sum(top-k) = sum_{>T} + (k-cnt_gt)*T — exact
// regardless of which tied indices the reference's stable sort picks.
__global__ __launch_bounds__(TPBS) void select_kernel(
    const float* __restrict__ mined, const float* __restrict__ part_ll,
    const float* __restrict__ part_pc, const int* __restrict__ part_np,
    float* __restrict__ ll_batch, float* __restrict__ lc_batch,
    int* __restrict__ np_batch, int P, int CB, int ratio) {
    const int b = blockIdx.x, tid = threadIdx.x;
    const int lane = tid & 63, wv = tid >> 6;
    constexpr int W = TPBS / 64;  // 16 waves
    const float* v = mined + (size_t)b * P;
    const int NIT = (P + TPBS - 1) / TPBS;
    const bool cached = (NIT <= RCAP);

    __shared__ float s_wf[W], s_wg[W];
    __shared__ int s_wi[W];
    __shared__ int s_hist[W * 256];
    __shared__ int s_wt[4];
    __shared__ unsigned s_bsel;
    __shared__ int s_krn;
    __shared__ float s_bc[2];
    __shared__ int s_bn;

    // register-cache the batch row (single global sweep)
    float rv[RCAP];
    if (cached) {
        for (int it = 0; it < NIT; ++it) {
            int p = tid + it * TPBS;
            rv[it] = (p < P) ? v[p] : 0.0f;
        }
    }

    // merged partial reduction (2 barriers total)
    float pll = 0.0f, ppc = 0.0f;
    int pnp = 0;
    for (int i = tid; i < CB; i += TPBS) {
        pll += part_ll[b * CB + i];
        ppc += part_pc[b * CB + i];
        pnp += part_np[b * CB + i];
    }
#pragma unroll
    for (int d = 1; d < 64; d <<= 1) {
        pll += __shfl_xor(pll, d, 64);
        ppc += __shfl_xor(ppc, d, 64);
        pnp += __shfl_xor(pnp, d, 64);
    }
    if (lane == 0) { s_wf[wv] = pll; s_wg[wv] = ppc; s_wi[wv] = pnp; }
    __syncthreads();
    if (tid == 0) {
        float L = 0.f, Pc = 0.f;
        int N = 0;
        for (int w = 0; w < W; ++w) { L += s_wf[w]; Pc += s_wg[w]; N += s_wi[w]; }
        s_bc[0] = L; s_bc[1] = Pc; s_bn = N;
    }
    __syncthreads();
    const float ll_sum = s_bc[0];
    const float sum_pos = s_bc[1];
    const int npos = s_bn;

    const int k = min(ratio * npos, P - npos);
    if (tid == 0) {
        ll_batch[b] = ll_sum;
        np_batch[b] = npos;
    }
    if (k <= 0) {
        if (tid == 0) lc_batch[b] = sum_pos;
        return;
    }

    unsigned prefix = 0u;
    int kr = k;
    for (int pass = 0; pass < 4; ++pass) {
        const int shift = 24 - 8 * pass;
        const unsigned mask = (pass == 0) ? 0u : (0xFFFFFFFFu << (32 - 8 * pass));
        for (int i = tid; i < W * 256; i += TPBS) s_hist[i] = 0;
        __syncthreads();
        for (int it = 0; it < NIT; ++it) {
            int p = tid + it * TPBS;
            if (p < P) {
                unsigned u = __float_as_uint(cached ? rv[it] : v[p]);
                if ((u & mask) == prefix)
                    atomicAdd(&s_hist[wv * 256 + ((u >> shift) & 0xFF)], 1);
            }
        }
        __syncthreads();
        int sge = 0, h = 0;
        if (tid < 256) {
            for (int w = 0; w < W; ++w) h += s_hist[w * 256 + tid];
            // intra-wave inclusive suffix scan over the 64 bins this wave owns
            int val = h;
#pragma unroll
            for (int d = 1; d < 64; d <<= 1) {
                int t = __shfl_down(val, d, 64);
                if (lane + d < 64) val += t;
            }
            if (lane == 0) s_wt[tid >> 6] = val;  // wave-chunk total
            sge = val;
        }
        __syncthreads();
        if (tid < 256) {
            for (int w = (tid >> 6) + 1; w < 4; ++w) sge += s_wt[w];
            int sgt = sge - h;
            if (sge >= kr && sgt < kr) {  // exactly one tid satisfies
                s_bsel = (unsigned)tid;
                s_krn = kr - sgt;
            }
        }
        __syncthreads();
        prefix |= s_bsel << shift;
        kr = s_krn;
        // no trailing barrier: s_bsel/s_krn are next written only after two
        // barriers of the following pass
    }
    const float T = __uint_as_float(prefix);  // exact k-th largest value
    float lsum = 0.0f;
    int lcnt = 0;
    for (int it = 0; it < NIT; ++it) {
        int p = tid + it * TPBS;
        if (p < P) {
            float x = cached ? rv[it] : v[p];
            if (x > T) { lsum += x; ++lcnt; }
        }
    }
#pragma unroll
    for (int d = 1; d < 64; d <<= 1) {
        lsum += __shfl_xor(lsum, d, 64);
        lcnt += __shfl_xor(lcnt, d, 64);
    }
    if (lane == 0) { s_wf[wv] = lsum; s_wi[wv] = lcnt; }
    __syncthreads();
    if (tid == 0) {
        float S = 0.f;
        int Cn = 0;
        for (int w = 0; w < W; ++w) { S += s_wf[w]; Cn += s_wi[w]; }
        lc_batch[b] = sum_pos + S + (float)(k - Cn) * T;
    }
}

__global__ __launch_bounds__(TPB) void finalize_kernel(
    const float* __restrict__ ll_batch, const int* __restrict__ np_batch,
    const float* __restrict__ lc_batch, int B, float* __restrict__ out) {
    const int tid = threadIdx.x;
    __shared__ float s_l[TPB], s_c[TPB];
    __shared__ int s_n[TPB];
    float l = 0.0f, c = 0.0f;
    int n = 0;
    for (int i = tid; i < B; i += TPB) {
        l += ll_batch[i];
        c += lc_batch[i];
        n += np_batch[i];
    }
    s_l[tid] = l; s_c[tid] = c; s_n[tid] = n;
    __syncthreads();
    for (int s = TPB / 2; s > 0; s >>= 1) {
        if (tid < s) {
            s_l[tid] += s_l[tid + s];
            s_c[tid] += s_c[tid + s];
            s_n[tid] += s_n[tid + s];
        }
        __syncthreads();
    }
    if (tid == 0) {
        float N = (float)s_n[0];
        out[0] = s_l[0] / N;
        out[1] = s_c[0] / N;
    }
}

extern "C" void kernel_launch(void* const* d_in, const int* in_sizes, int n_in,
                              void* d_out, int out_size, void* d_ws, size_t ws_size,
                              hipStream_t stream) {
    const float* loc = (const float*)d_in[0];
    const float* conf = (const float*)d_in[1];
    const float* priors = (const float*)d_in[2];
    const float* targets = (const float*)d_in[3];

    const int P = in_sizes[2] / 4;
    const int B = in_sizes[0] / (P * 4);
    const int C = in_sizes[1] / (in_sizes[0] / 4);  // conf / (B*P)
    const int O = in_sizes[3] / (B * 5);
    const size_t BP = (size_t)B * P;
    const int S1 = (P + CHP - 1) / CHP;    // match1 chunks per batch
    const int CB2 = (P + TPB - 1) / TPB;   // m2c chunks per batch

    // ws layout (8B-aligned first; everything fully written before read):
    ull* pkeys = (ull*)d_ws;                                // B*O*S1 u64
    float* mined = (float*)(pkeys + (size_t)B * O * S1);    // BP f32
    float* part_ll = mined + BP;                            // B*CB2 f32
    float* part_pc = part_ll + (size_t)B * CB2;             // B*CB2 f32
    int* part_np = (int*)(part_pc + (size_t)B * CB2);       // B*CB2 i32
    float* ll_batch = (float*)(part_np + (size_t)B * CB2);  // B f32
    float* lc_batch = ll_batch + B;                         // B f32
    int* np_batch = (int*)(lc_batch + B);                   // B i32

    if (O == 8) {
        match1_kernel<8><<<B * S1, TPB, 0, stream>>>(priors, targets, P, O, S1, pkeys);
        if (C == 21) {
            m2c_kernel<8, 21><<<B * CB2, TPB, 0, stream>>>(
                loc, priors, targets, conf, pkeys, P, O, C, S1, CB2,
                mined, part_ll, part_pc, part_np);
        } else {
            m2c_kernel<8, 0><<<B * CB2, TPB, 0, stream>>>(
                loc, priors, targets, conf, pkeys, P, O, C, S1, CB2,
                mined, part_ll, part_pc, part_np);
        }
    } else {
        match1_kernel<0><<<B * S1, TPB, 0, stream>>>(priors, targets, P, O, S1, pkeys);
        m2c_kernel<0, 0><<<B * CB2, TPB, 0, stream>>>(
            loc, priors, targets, conf, pkeys, P, O, C, S1, CB2,
            mined, part_ll, part_pc, part_np);
    }

    select_kernel<<<B, TPBS, 0, stream>>>(mined, part_ll, part_pc, part_np,
                                          ll_batch, lc_batch, np_batch, P, CB2, 3);

    finalize_kernel<<<1, TPB, 0, stream>>>(ll_batch, np_batch, lc_batch, B,
                                           (float*)d_out);
}